// Round 2
// baseline (1279.902 us; speedup 1.0000x reference)
//
#include <hip/hip_runtime.h>
#include <hip/hip_bf16.h>

#define N_NODES 50000
#define E_EDGES 800000
#define HID 128
#define HEADS 4
#define OUT_DIM 32
#define NEG_SLOPE 0.2f
#define LN_EPS 1e-5f

#define PARAM_FLOATS 17024  // W(16384) al(128) ar(128) b(128) g(128) be(128)

__device__ __forceinline__ float bf2f(__hip_bfloat16 b) { return __bfloat162float(b); }

// Order-preserving float<->uint encoding for atomicMax on floats (incl. negatives)
__device__ __forceinline__ unsigned int f2ord(float f) {
    unsigned int u = __float_as_uint(f);
    return (u & 0x80000000u) ? ~u : (u | 0x80000000u);
}
__device__ __forceinline__ float ord2f(unsigned int u) {
    u = (u & 0x80000000u) ? (u & 0x7FFFFFFFu) : ~u;
    return __uint_as_float(u);
}

// ---------- runtime dtype detection ----------
// If W0 is packed bf16, the fp32 value built from each u32 word's LOW 16 bits
// is a valid weight (|v| in [1e-6,1]) with ~certainty. If W0 is fp32, the low
// half is random mantissa bits -> ~11% hit rate. flag=1 means bf16 inputs.
__global__ __launch_bounds__(256) void detect_kernel(const unsigned int* __restrict__ w0,
                                                     unsigned int* __restrict__ flag) {
    int t = threadIdx.x;
    int cnt = 0;
    for (int i = t; i < 4096; i += 256) {
        unsigned int lo = (w0[i] & 0xFFFFu) << 16;
        float v = fabsf(__uint_as_float(lo));
        if (v >= 1e-6f && v <= 1.0f) cnt++;
    }
    __shared__ int sh[4];
#pragma unroll
    for (int off = 32; off >= 1; off >>= 1) cnt += __shfl_xor(cnt, off);
    if ((t & 63) == 0) sh[t >> 6] = cnt;
    __syncthreads();
    if (t == 0) {
        int tot = sh[0] + sh[1] + sh[2] + sh[3];
        *flag = (tot > 2048) ? 1u : 0u;
    }
}

__device__ __forceinline__ float load_any(const void* p, int i, unsigned int isbf16) {
    return isbf16 ? bf2f(((const __hip_bfloat16*)p)[i]) : ((const float*)p)[i];
}

// ---------- features -> fp32 ----------
__global__ __launch_bounds__(256) void cvt_feat_kernel(const void* __restrict__ f,
                                                       const unsigned int* __restrict__ flag,
                                                       float* __restrict__ x, int n) {
    int i = blockIdx.x * 256 + threadIdx.x;
    if (i >= n) return;
    x[i] = load_any(f, i, *flag);
}

// ---------- per-layer params -> fp32 contiguous block ----------
__global__ __launch_bounds__(256) void cvt_params_kernel(const void* W, const void* al,
                                                         const void* ar, const void* b,
                                                         const void* g, const void* be,
                                                         const unsigned int* __restrict__ flag,
                                                         float* __restrict__ out) {
    int i = blockIdx.x * 256 + threadIdx.x;
    if (i >= PARAM_FLOATS) return;
    unsigned int isb = *flag;
    const void* src; int off;
    if (i < 16384)      { src = W;  off = i; }
    else if (i < 16512) { src = al; off = i - 16384; }
    else if (i < 16640) { src = ar; off = i - 16512; }
    else if (i < 16768) { src = b;  off = i - 16640; }
    else if (i < 16896) { src = g;  off = i - 16768; }
    else                { src = be; off = i - 16896; }
    out[i] = load_any(src, off, isb);
}

// ---------- h = x @ W   (x: [M,128] fp32, W: [128,128] fp32, h: [M,128] fp32) ----------
#define GEMM_BM 32
__global__ __launch_bounds__(256) void gemm_kernel(const float* __restrict__ x,
                                                   const float* __restrict__ W,
                                                   float* __restrict__ h, int M) {
    __shared__ float ws[64][128];
    __shared__ float xs[GEMM_BM][128];
    int t = threadIdx.x;
    int row0 = blockIdx.x * GEMM_BM;

    for (int i = t; i < GEMM_BM * 128; i += 256) {
        int r = i >> 7, c = i & 127;
        int gr = row0 + r;
        xs[r][c] = (gr < M) ? x[gr * 128 + c] : 0.f;
    }

    int r = t >> 3;
    int c0 = (t & 7) * 16;
    float acc[16];
#pragma unroll
    for (int i = 0; i < 16; i++) acc[i] = 0.f;

    for (int kt = 0; kt < 2; ++kt) {
        for (int i = t; i < 64 * 128; i += 256) {
            int kk = i >> 7, c = i & 127;
            ws[kk][c] = W[(kt * 64 + kk) * 128 + c];
        }
        __syncthreads();
        for (int k = 0; k < 64; ++k) {
            float xv = xs[r][kt * 64 + k];
            const float4* wr = (const float4*)&ws[k][c0];
            float4 w0 = wr[0], w1 = wr[1], w2 = wr[2], w3 = wr[3];
            acc[0] = fmaf(xv, w0.x, acc[0]);  acc[1] = fmaf(xv, w0.y, acc[1]);
            acc[2] = fmaf(xv, w0.z, acc[2]);  acc[3] = fmaf(xv, w0.w, acc[3]);
            acc[4] = fmaf(xv, w1.x, acc[4]);  acc[5] = fmaf(xv, w1.y, acc[5]);
            acc[6] = fmaf(xv, w1.z, acc[6]);  acc[7] = fmaf(xv, w1.w, acc[7]);
            acc[8] = fmaf(xv, w2.x, acc[8]);  acc[9] = fmaf(xv, w2.y, acc[9]);
            acc[10] = fmaf(xv, w2.z, acc[10]); acc[11] = fmaf(xv, w2.w, acc[11]);
            acc[12] = fmaf(xv, w3.x, acc[12]); acc[13] = fmaf(xv, w3.y, acc[13]);
            acc[14] = fmaf(xv, w3.z, acc[14]); acc[15] = fmaf(xv, w3.w, acc[15]);
        }
        __syncthreads();
    }

    int gr = row0 + r;
    if (gr < M) {
#pragma unroll
        for (int i = 0; i < 16; i++) h[gr * 128 + c0 + i] = acc[i];
    }
}

// ---------- el/er: per-node per-head dot(h, al/ar). One 64-lane wave per node. ----------
__global__ __launch_bounds__(256) void scores_kernel(const float* __restrict__ h,
                                                     const float* __restrict__ al,
                                                     const float* __restrict__ ar,
                                                     float* __restrict__ el,
                                                     float* __restrict__ er, int M) {
    int node = (blockIdx.x * 256 + threadIdx.x) >> 6;
    int lane = threadIdx.x & 63;
    if (node >= M) return;
    const float* hr = h + node * 128;
    float h0 = hr[lane], h1 = hr[lane + 64];
    float pl0 = h0 * al[lane], pl1 = h1 * al[lane + 64];
    float pr0 = h0 * ar[lane], pr1 = h1 * ar[lane + 64];
#pragma unroll
    for (int off = 16; off >= 1; off >>= 1) {
        pl0 += __shfl_xor(pl0, off);
        pl1 += __shfl_xor(pl1, off);
        pr0 += __shfl_xor(pr0, off);
        pr1 += __shfl_xor(pr1, off);
    }
    if (lane == 0)  { el[node * 4 + 0] = pl0; el[node * 4 + 2] = pl1;
                      er[node * 4 + 0] = pr0; er[node * 4 + 2] = pr1; }
    if (lane == 32) { el[node * 4 + 1] = pl0; el[node * 4 + 3] = pl1;
                      er[node * 4 + 1] = pr0; er[node * 4 + 3] = pr1; }
}

// ---------- segment max over dst via ordered-uint atomicMax ----------
__global__ __launch_bounds__(256) void edge_max_kernel(const int* __restrict__ src,
                                                       const int* __restrict__ dst,
                                                       const float* __restrict__ el,
                                                       const float* __restrict__ er,
                                                       unsigned int* __restrict__ m_ord) {
    int i = blockIdx.x * 256 + threadIdx.x;
    if (i >= E_EDGES * HEADS) return;
    int e = i >> 2, hd = i & 3;
    int s = src[e], d = dst[e];
    float v = el[s * 4 + hd] + er[d * 4 + hd];
    v = v > 0.f ? v : v * NEG_SLOPE;
    atomicMax(&m_ord[d * 4 + hd], f2ord(v));
}

// ---------- exp + denom-sum + unnormalized message aggregation ----------
__global__ __launch_bounds__(256) void edge_agg_kernel(const int* __restrict__ src,
                                                       const int* __restrict__ dst,
                                                       const float* __restrict__ el,
                                                       const float* __restrict__ er,
                                                       const unsigned int* __restrict__ m_ord,
                                                       const float* __restrict__ h,
                                                       float* __restrict__ denom,
                                                       float* __restrict__ acc) {
    int i = blockIdx.x * 256 + threadIdx.x;
    int e = i >> 7;
    if (e >= E_EDGES) return;
    int c = i & 127, hd = c >> 5;
    int s = src[e], d = dst[e];
    float v = el[s * 4 + hd] + er[d * 4 + hd];
    v = v > 0.f ? v : v * NEG_SLOPE;
    float m = ord2f(m_ord[d * 4 + hd]);
    float ex = __expf(v - m);
    if ((c & 31) == 0) atomicAdd(&denom[d * 4 + hd], ex);
    atomicAdd(&acc[d * 128 + c], ex * h[s * 128 + c]);
}

// ---------- /denom + bias -> LayerNorm -> ELU. One 64-lane wave per node. ----------
template <bool LAST>
__global__ __launch_bounds__(256) void epilogue_kernel(const float* acc,
                                                       const float* __restrict__ denom,
                                                       const float* __restrict__ params,
                                                       const unsigned int* __restrict__ flag,
                                                       float* x_next,
                                                       void* out) {
    int node = (blockIdx.x * 256 + threadIdx.x) >> 6;
    int lane = threadIdx.x & 63;
    if (node >= N_NODES) return;
    const float* b  = params + 16640;
    const float* g  = params + 16768;
    const float* be = params + 16896;
    int c0 = lane, c1 = lane + 64;
    float d0 = denom[node * 4 + (c0 >> 5)];
    float d1 = denom[node * 4 + (c1 >> 5)];
    float v0 = acc[node * 128 + c0] / fmaxf(d0, 1e-9f) + b[c0];
    float v1 = acc[node * 128 + c1] / fmaxf(d1, 1e-9f) + b[c1];
    float s = v0 + v1;
#pragma unroll
    for (int off = 32; off >= 1; off >>= 1) s += __shfl_xor(s, off);
    float mu = s * (1.f / 128.f);
    float q0 = v0 - mu, q1 = v1 - mu;
    float vs = q0 * q0 + q1 * q1;
#pragma unroll
    for (int off = 32; off >= 1; off >>= 1) vs += __shfl_xor(vs, off);
    float rstd = rsqrtf(vs * (1.f / 128.f) + LN_EPS);
    float y0 = q0 * rstd * g[c0] + be[c0];
    float y1 = q1 * rstd * g[c1] + be[c1];
    y0 = y0 > 0.f ? y0 : expm1f(y0);
    y1 = y1 > 0.f ? y1 : expm1f(y1);
    if (LAST) {
        if (*flag) {
            __hip_bfloat16* o = (__hip_bfloat16*)out;
            o[node * 128 + c0] = __float2bfloat16(y0);
            o[node * 128 + c1] = __float2bfloat16(y1);
        } else {
            float* o = (float*)out;
            o[node * 128 + c0] = y0;
            o[node * 128 + c1] = y1;
        }
    } else {
        x_next[node * 128 + c0] = y0;
        x_next[node * 128 + c1] = y1;
    }
}

extern "C" void kernel_launch(void* const* d_in, const int* in_sizes, int n_in,
                              void* d_out, int out_size, void* d_ws, size_t ws_size,
                              hipStream_t stream) {
    const void* features = d_in[0];
    const int* src = (const int*)d_in[1];
    const int* dst = (const int*)d_in[2];

    char* w = (char*)d_ws;
    float* bufA = (float*)w;                                     // 25.6 MB: x / acc
    float* bufH = (float*)(w + 25600000);                        // 25.6 MB: h
    float* el = (float*)(w + 51200000);                          // 800 KB
    float* er = el + N_NODES * HEADS;                            // 800 KB
    unsigned int* m_ord = (unsigned int*)(er + N_NODES * HEADS); // 800 KB
    float* denom = (float*)(m_ord + N_NODES * HEADS);            // 800 KB
    float* params0 = denom + N_NODES * HEADS;                    // 68 KB
    float* params1 = params0 + PARAM_FLOATS;                     // 68 KB
    unsigned int* flag = (unsigned int*)(params1 + PARAM_FLOATS);

    detect_kernel<<<1, 256, 0, stream>>>((const unsigned int*)d_in[3], flag);
    cvt_feat_kernel<<<(N_NODES * HID + 255) / 256, 256, 0, stream>>>(features, flag, bufA,
                                                                     N_NODES * HID);
    cvt_params_kernel<<<(PARAM_FLOATS + 255) / 256, 256, 0, stream>>>(
        d_in[3], d_in[4], d_in[5], d_in[6], d_in[7], d_in[8], flag, params0);
    cvt_params_kernel<<<(PARAM_FLOATS + 255) / 256, 256, 0, stream>>>(
        d_in[9], d_in[10], d_in[11], d_in[12], d_in[13], d_in[14], flag, params1);

    for (int l = 0; l < 2; ++l) {
        float* params = (l == 0) ? params0 : params1;
        gemm_kernel<<<(N_NODES + GEMM_BM - 1) / GEMM_BM, 256, 0, stream>>>(bufA, params, bufH,
                                                                            N_NODES);
        scores_kernel<<<(N_NODES * 64 + 255) / 256, 256, 0, stream>>>(bufH, params + 16384,
                                                                      params + 16512, el, er,
                                                                      N_NODES);
        hipMemsetAsync(bufA, 0, (size_t)N_NODES * HID * sizeof(float), stream);
        hipMemsetAsync(m_ord, 0, (size_t)N_NODES * HEADS * 2 * sizeof(float), stream);

        edge_max_kernel<<<(E_EDGES * HEADS + 255) / 256, 256, 0, stream>>>(src, dst, el, er,
                                                                           m_ord);
        edge_agg_kernel<<<(E_EDGES * HID + 255) / 256, 256, 0, stream>>>(src, dst, el, er,
                                                                          m_ord, bufH, denom,
                                                                          bufA);
        if (l == 0) {
            epilogue_kernel<false><<<(N_NODES * 64 + 255) / 256, 256, 0, stream>>>(
                bufA, denom, params, flag, bufA, nullptr);
        } else {
            epilogue_kernel<true><<<(N_NODES * 64 + 255) / 256, 256, 0, stream>>>(
                bufA, denom, params, flag, nullptr, d_out);
        }
    }
}

// Round 3
// 631.399 us; speedup vs baseline: 2.0271x; 2.0271x over previous
//
#include <hip/hip_runtime.h>
#include <hip/hip_bf16.h>

#define N_NODES 50000
#define E_EDGES 800000
#define HID 128
#define HEADS 4
#define NEG_SLOPE 0.2f
#define LN_EPS 1e-5f

#define PARAM_FLOATS 17024  // W(16384) al(128) ar(128) b(128) g(128) be(128)

__device__ __forceinline__ float bf2f(__hip_bfloat16 b) { return __bfloat162float(b); }

// ---------- runtime dtype detection (bf16 vs fp32 input buffers) ----------
__global__ __launch_bounds__(256) void detect_kernel(const unsigned int* __restrict__ w0,
                                                     unsigned int* __restrict__ flag) {
    int t = threadIdx.x;
    int cnt = 0;
    for (int i = t; i < 4096; i += 256) {
        unsigned int lo = (w0[i] & 0xFFFFu) << 16;
        float v = fabsf(__uint_as_float(lo));
        if (v >= 1e-6f && v <= 1.0f) cnt++;
    }
    __shared__ int sh[4];
#pragma unroll
    for (int off = 32; off >= 1; off >>= 1) cnt += __shfl_xor(cnt, off);
    if ((t & 63) == 0) sh[t >> 6] = cnt;
    __syncthreads();
    if (t == 0) *flag = ((sh[0] + sh[1] + sh[2] + sh[3]) > 2048) ? 1u : 0u;
}

__device__ __forceinline__ float load_any(const void* p, int i, unsigned int isbf16) {
    return isbf16 ? bf2f(((const __hip_bfloat16*)p)[i]) : ((const float*)p)[i];
}

__global__ __launch_bounds__(256) void cvt_feat_kernel(const void* __restrict__ f,
                                                       const unsigned int* __restrict__ flag,
                                                       float* __restrict__ x, int n) {
    int i = blockIdx.x * 256 + threadIdx.x;
    if (i >= n) return;
    x[i] = load_any(f, i, *flag);
}

__global__ __launch_bounds__(256) void cvt_params_kernel(const void* W, const void* al,
                                                         const void* ar, const void* b,
                                                         const void* g, const void* be,
                                                         const unsigned int* __restrict__ flag,
                                                         float* __restrict__ out) {
    int i = blockIdx.x * 256 + threadIdx.x;
    if (i >= PARAM_FLOATS) return;
    unsigned int isb = *flag;
    const void* src; int off;
    if (i < 16384)      { src = W;  off = i; }
    else if (i < 16512) { src = al; off = i - 16384; }
    else if (i < 16640) { src = ar; off = i - 16512; }
    else if (i < 16768) { src = b;  off = i - 16640; }
    else if (i < 16896) { src = g;  off = i - 16768; }
    else                { src = be; off = i - 16896; }
    out[i] = load_any(src, off, isb);
}

// ---------- CSR build: histogram -> scan -> scatter ----------
__global__ __launch_bounds__(256) void hist_kernel(const int* __restrict__ dst,
                                                   int* __restrict__ deg) {
    int i = blockIdx.x * 256 + threadIdx.x;
    if (i < E_EDGES) atomicAdd(&deg[dst[i]], 1);
}

__global__ __launch_bounds__(1024) void scan_kernel(const int* __restrict__ deg,
                                                    int* __restrict__ offs) {
    __shared__ int wtot[16];
    __shared__ int woff[16];
    __shared__ int total_s;
    __shared__ int carry_s;
    int t = threadIdx.x;
    int lane = t & 63, wid = t >> 6;
    if (t == 0) carry_s = 0;
    __syncthreads();
    for (int base = 0; base < N_NODES; base += 1024) {
        int carry = carry_s;
        int i = base + t;
        int v = (i < N_NODES) ? deg[i] : 0;
        int x = v;
#pragma unroll
        for (int o = 1; o < 64; o <<= 1) {
            int y = __shfl_up(x, o);
            if (lane >= o) x += y;
        }
        if (lane == 63) wtot[wid] = x;
        __syncthreads();
        if (wid == 0) {
            int ws = (lane < 16) ? wtot[lane] : 0;
            int xs = ws;
#pragma unroll
            for (int o = 1; o < 16; o <<= 1) {
                int y = __shfl_up(xs, o);
                if (lane >= o) xs += y;
            }
            if (lane < 16) woff[lane] = xs - ws;
            if (lane == 15) total_s = xs;
        }
        __syncthreads();
        if (i < N_NODES) offs[i] = carry + woff[wid] + (x - v);
        __syncthreads();
        if (t == 0) carry_s = carry + total_s;
        __syncthreads();
    }
    if (t == 0) offs[N_NODES] = E_EDGES;
}

__global__ __launch_bounds__(256) void scatter_kernel(const int* __restrict__ src,
                                                      const int* __restrict__ dst,
                                                      const int* __restrict__ offs,
                                                      int* __restrict__ cnt,
                                                      int* __restrict__ esrc) {
    int i = blockIdx.x * 256 + threadIdx.x;
    if (i >= E_EDGES) return;
    int d = dst[i];
    int pos = offs[d] + atomicAdd(&cnt[d], 1);
    esrc[pos] = src[i];
}

// ---------- h = x @ W ----------
#define GEMM_BM 32
__global__ __launch_bounds__(256) void gemm_kernel(const float* __restrict__ x,
                                                   const float* __restrict__ W,
                                                   float* __restrict__ h, int M) {
    __shared__ float ws[64][128];
    __shared__ float xs[GEMM_BM][128];
    int t = threadIdx.x;
    int row0 = blockIdx.x * GEMM_BM;

    for (int i = t; i < GEMM_BM * 128; i += 256) {
        int r = i >> 7, c = i & 127;
        int gr = row0 + r;
        xs[r][c] = (gr < M) ? x[gr * 128 + c] : 0.f;
    }

    int r = t >> 3;
    int c0 = (t & 7) * 16;
    float acc[16];
#pragma unroll
    for (int i = 0; i < 16; i++) acc[i] = 0.f;

    for (int kt = 0; kt < 2; ++kt) {
        for (int i = t; i < 64 * 128; i += 256) {
            int kk = i >> 7, c = i & 127;
            ws[kk][c] = W[(kt * 64 + kk) * 128 + c];
        }
        __syncthreads();
        for (int k = 0; k < 64; ++k) {
            float xv = xs[r][kt * 64 + k];
            const float4* wr = (const float4*)&ws[k][c0];
            float4 w0 = wr[0], w1 = wr[1], w2 = wr[2], w3 = wr[3];
            acc[0] = fmaf(xv, w0.x, acc[0]);  acc[1] = fmaf(xv, w0.y, acc[1]);
            acc[2] = fmaf(xv, w0.z, acc[2]);  acc[3] = fmaf(xv, w0.w, acc[3]);
            acc[4] = fmaf(xv, w1.x, acc[4]);  acc[5] = fmaf(xv, w1.y, acc[5]);
            acc[6] = fmaf(xv, w1.z, acc[6]);  acc[7] = fmaf(xv, w1.w, acc[7]);
            acc[8] = fmaf(xv, w2.x, acc[8]);  acc[9] = fmaf(xv, w2.y, acc[9]);
            acc[10] = fmaf(xv, w2.z, acc[10]); acc[11] = fmaf(xv, w2.w, acc[11]);
            acc[12] = fmaf(xv, w3.x, acc[12]); acc[13] = fmaf(xv, w3.y, acc[13]);
            acc[14] = fmaf(xv, w3.z, acc[14]); acc[15] = fmaf(xv, w3.w, acc[15]);
        }
        __syncthreads();
    }

    int gr = row0 + r;
    if (gr < M) {
#pragma unroll
        for (int i = 0; i < 16; i++) h[gr * 128 + c0 + i] = acc[i];
    }
}

// ---------- el/er scores ----------
__global__ __launch_bounds__(256) void scores_kernel(const float* __restrict__ h,
                                                     const float* __restrict__ al,
                                                     const float* __restrict__ ar,
                                                     float* __restrict__ el,
                                                     float* __restrict__ er, int M) {
    int node = (blockIdx.x * 256 + threadIdx.x) >> 6;
    int lane = threadIdx.x & 63;
    if (node >= M) return;
    const float* hr = h + node * 128;
    float h0 = hr[lane], h1 = hr[lane + 64];
    float pl0 = h0 * al[lane], pl1 = h1 * al[lane + 64];
    float pr0 = h0 * ar[lane], pr1 = h1 * ar[lane + 64];
#pragma unroll
    for (int off = 16; off >= 1; off >>= 1) {
        pl0 += __shfl_xor(pl0, off);
        pl1 += __shfl_xor(pl1, off);
        pr0 += __shfl_xor(pr0, off);
        pr1 += __shfl_xor(pr1, off);
    }
    if (lane == 0)  { el[node * 4 + 0] = pl0; el[node * 4 + 2] = pl1;
                      er[node * 4 + 0] = pr0; er[node * 4 + 2] = pr1; }
    if (lane == 32) { el[node * 4 + 1] = pl0; el[node * 4 + 3] = pl1;
                      er[node * 4 + 1] = pr0; er[node * 4 + 3] = pr1; }
}

// ---------- fused: online-softmax aggregation + bias + LayerNorm + ELU ----------
// One 64-lane wave per dst node; lane owns channels (2*lane, 2*lane+1), head = lane>>4.
template <bool LAST>
__global__ __launch_bounds__(256) void agg_ln_kernel(const int* __restrict__ offs,
                                                     const int* __restrict__ esrc,
                                                     const float* __restrict__ el,
                                                     const float* __restrict__ er,
                                                     const float* __restrict__ h,
                                                     const float* __restrict__ params,
                                                     const unsigned int* __restrict__ flag,
                                                     float* __restrict__ x_next,
                                                     void* __restrict__ out) {
    int node = (blockIdx.x * 256 + threadIdx.x) >> 6;
    int lane = threadIdx.x & 63;
    if (node >= N_NODES) return;
    int hd = lane >> 4;
    int c0 = lane * 2;
    float er_d = er[node * 4 + hd];
    int e0 = offs[node], e1 = offs[node + 1];

    float m = -INFINITY, l = 0.f, a0 = 0.f, a1 = 0.f;
    for (int e = e0; e < e1; ++e) {
        int s = esrc[e];
        float v = el[s * 4 + hd] + er_d;
        v = v > 0.f ? v : v * NEG_SLOPE;
        float mn = fmaxf(m, v);
        float sc = __expf(m - mn);   // 0 on first iteration (m = -inf)
        float ev = __expf(v - mn);
        float2 hv = *(const float2*)(h + s * 128 + c0);
        l = fmaf(l, sc, ev);
        a0 = fmaf(a0, sc, ev * hv.x);
        a1 = fmaf(a1, sc, ev * hv.y);
        m = mn;
    }
    float inv = 1.f / fmaxf(l, 1e-9f);
    const float* b  = params + 16640;
    const float* g  = params + 16768;
    const float* be = params + 16896;
    float v0 = fmaf(a0, inv, b[c0]);
    float v1 = fmaf(a1, inv, b[c0 + 1]);

    float s = v0 + v1;
#pragma unroll
    for (int off = 32; off >= 1; off >>= 1) s += __shfl_xor(s, off);
    float mu = s * (1.f / 128.f);
    float q0 = v0 - mu, q1 = v1 - mu;
    float vs = q0 * q0 + q1 * q1;
#pragma unroll
    for (int off = 32; off >= 1; off >>= 1) vs += __shfl_xor(vs, off);
    float rstd = rsqrtf(vs * (1.f / 128.f) + LN_EPS);
    float y0 = q0 * rstd * g[c0] + be[c0];
    float y1 = q1 * rstd * g[c0 + 1] + be[c0 + 1];
    y0 = y0 > 0.f ? y0 : expm1f(y0);
    y1 = y1 > 0.f ? y1 : expm1f(y1);

    if (LAST) {
        if (*flag) {
            __hip_bfloat162* o = (__hip_bfloat162*)out;
            o[node * 64 + lane] = __hip_bfloat162(__float2bfloat16(y0), __float2bfloat16(y1));
        } else {
            float2* o = (float2*)out;
            o[node * 64 + lane] = make_float2(y0, y1);
        }
    } else {
        float2* o = (float2*)x_next;
        o[node * 64 + lane] = make_float2(y0, y1);
    }
}

extern "C" void kernel_launch(void* const* d_in, const int* in_sizes, int n_in,
                              void* d_out, int out_size, void* d_ws, size_t ws_size,
                              hipStream_t stream) {
    const void* features = d_in[0];
    const int* src = (const int*)d_in[1];
    const int* dst = (const int*)d_in[2];

    char* w = (char*)d_ws;
    float* bufA = (float*)w;                          // 25.6 MB: x / x_next
    float* bufH = (float*)(w + 25600000);             // 25.6 MB: h
    float* el   = (float*)(w + 51200000);             // 800 KB
    float* er   = el + N_NODES * HEADS;               // 800 KB
    float* params0 = er + N_NODES * HEADS;            // 68 KB
    float* params1 = params0 + PARAM_FLOATS;          // 68 KB
    int* offs = (int*)(params1 + PARAM_FLOATS);       // 50001 ints
    int* deg  = offs + N_NODES + 1;                   // 50000 ints (reused as cursor)
    int* esrc = deg + N_NODES;                        // 800000 ints
    unsigned int* flag = (unsigned int*)(esrc + E_EDGES);

    detect_kernel<<<1, 256, 0, stream>>>((const unsigned int*)d_in[3], flag);
    cvt_feat_kernel<<<(N_NODES * HID + 255) / 256, 256, 0, stream>>>(features, flag, bufA,
                                                                     N_NODES * HID);
    cvt_params_kernel<<<(PARAM_FLOATS + 255) / 256, 256, 0, stream>>>(
        d_in[3], d_in[4], d_in[5], d_in[6], d_in[7], d_in[8], flag, params0);
    cvt_params_kernel<<<(PARAM_FLOATS + 255) / 256, 256, 0, stream>>>(
        d_in[9], d_in[10], d_in[11], d_in[12], d_in[13], d_in[14], flag, params1);

    // CSR build (per launch; reused by both layers)
    hipMemsetAsync(deg, 0, N_NODES * sizeof(int), stream);
    hist_kernel<<<(E_EDGES + 255) / 256, 256, 0, stream>>>(dst, deg);
    scan_kernel<<<1, 1024, 0, stream>>>(deg, offs);
    hipMemsetAsync(deg, 0, N_NODES * sizeof(int), stream);
    scatter_kernel<<<(E_EDGES + 255) / 256, 256, 0, stream>>>(src, dst, offs, deg, esrc);

    for (int l = 0; l < 2; ++l) {
        float* params = (l == 0) ? params0 : params1;
        gemm_kernel<<<(N_NODES + GEMM_BM - 1) / GEMM_BM, 256, 0, stream>>>(bufA, params, bufH,
                                                                            N_NODES);
        scores_kernel<<<(N_NODES * 64 + 255) / 256, 256, 0, stream>>>(bufH, params + 16384,
                                                                      params + 16512, el, er,
                                                                      N_NODES);
        if (l == 0) {
            agg_ln_kernel<false><<<(N_NODES * 64 + 255) / 256, 256, 0, stream>>>(
                offs, esrc, el, er, bufH, params, flag, bufA, nullptr);
        } else {
            agg_ln_kernel<true><<<(N_NODES * 64 + 255) / 256, 256, 0, stream>>>(
                offs, esrc, el, er, bufH, params, flag, nullptr, d_out);
        }
    }
}

// Round 5
// 530.945 us; speedup vs baseline: 2.4106x; 1.1892x over previous
//
#include <hip/hip_runtime.h>
#include <hip/hip_bf16.h>

#define N_NODES 50000
#define E_EDGES 800000
#define HID 128
#define HEADS 4
#define NEG_SLOPE 0.2f
#define LN_EPS 1e-5f
#define PARAM_FLOATS 17024  // W(16384) al(128) ar(128) b(128) g(128) be(128)

__device__ __forceinline__ float bf2f(__hip_bfloat16 b) { return __bfloat162float(b); }

// ---------- runtime dtype detection (bf16 vs fp32 input buffers) ----------
// Evidence so far says flag==0 (fp32), but keep the (cheap, proven) detector.
__global__ __launch_bounds__(256) void detect_kernel(const unsigned int* __restrict__ w0,
                                                     unsigned int* __restrict__ flag) {
    int t = threadIdx.x;
    int cnt = 0;
    for (int i = t; i < 4096; i += 256) {
        unsigned int lo = (w0[i] & 0xFFFFu) << 16;
        float v = fabsf(__uint_as_float(lo));
        if (v >= 1e-6f && v <= 1.0f) cnt++;
    }
    __shared__ int sh[4];
#pragma unroll
    for (int off = 32; off >= 1; off >>= 1) cnt += __shfl_xor(cnt, off);
    if ((t & 63) == 0) sh[t >> 6] = cnt;
    __syncthreads();
    if (t == 0) *flag = ((sh[0] + sh[1] + sh[2] + sh[3]) > 2048) ? 1u : 0u;
}

__device__ __forceinline__ float load_any(const void* p, int i, unsigned int isbf16) {
    return isbf16 ? bf2f(((const __hip_bfloat16*)p)[i]) : ((const float*)p)[i];
}

__global__ __launch_bounds__(256) void cvt_feat_kernel(const void* __restrict__ f,
                                                       const unsigned int* __restrict__ flag,
                                                       float* __restrict__ x, int n) {
    int i = blockIdx.x * 256 + threadIdx.x;
    if (i >= n) return;
    x[i] = load_any(f, i, *flag);
}

__global__ __launch_bounds__(256) void cvt_params_kernel(const void* W, const void* al,
                                                         const void* ar, const void* b,
                                                         const void* g, const void* be,
                                                         const unsigned int* __restrict__ flag,
                                                         float* __restrict__ out) {
    int i = blockIdx.x * 256 + threadIdx.x;
    if (i >= PARAM_FLOATS) return;
    unsigned int isb = *flag;
    const void* src; int off;
    if (i < 16384)      { src = W;  off = i; }
    else if (i < 16512) { src = al; off = i - 16384; }
    else if (i < 16640) { src = ar; off = i - 16512; }
    else if (i < 16768) { src = b;  off = i - 16640; }
    else if (i < 16896) { src = g;  off = i - 16768; }
    else                { src = be; off = i - 16896; }
    out[i] = load_any(src, off, isb);
}

// ---------- CSR build ----------
__global__ __launch_bounds__(256) void hist_kernel(const int* __restrict__ dst,
                                                   int* __restrict__ deg) {
    int i = blockIdx.x * 256 + threadIdx.x;
    if (i < E_EDGES) atomicAdd(&deg[dst[i]], 1);
}

__global__ __launch_bounds__(1024) void scan_kernel(const int* __restrict__ deg,
                                                    int* __restrict__ offs) {
    __shared__ int wtot[16];
    __shared__ int woff[16];
    __shared__ int total_s;
    __shared__ int carry_s;
    int t = threadIdx.x;
    int lane = t & 63, wid = t >> 6;
    if (t == 0) carry_s = 0;
    __syncthreads();
    for (int base = 0; base < N_NODES; base += 1024) {
        int carry = carry_s;
        int i = base + t;
        int v = (i < N_NODES) ? deg[i] : 0;
        int x = v;
#pragma unroll
        for (int o = 1; o < 64; o <<= 1) {
            int y = __shfl_up(x, o);
            if (lane >= o) x += y;
        }
        if (lane == 63) wtot[wid] = x;
        __syncthreads();
        if (wid == 0) {
            int ws = (lane < 16) ? wtot[lane] : 0;
            int xs = ws;
#pragma unroll
            for (int o = 1; o < 16; o <<= 1) {
                int y = __shfl_up(xs, o);
                if (lane >= o) xs += y;
            }
            if (lane < 16) woff[lane] = xs - ws;
            if (lane == 15) total_s = xs;
        }
        __syncthreads();
        if (i < N_NODES) offs[i] = carry + woff[wid] + (x - v);
        __syncthreads();
        if (t == 0) carry_s = carry + total_s;
        __syncthreads();
    }
    if (t == 0) offs[N_NODES] = E_EDGES;
}

__global__ __launch_bounds__(256) void scatter_kernel(const int* __restrict__ src,
                                                      const int* __restrict__ dst,
                                                      const int* __restrict__ offs,
                                                      int* __restrict__ cnt,
                                                      int* __restrict__ esrc) {
    int i = blockIdx.x * 256 + threadIdx.x;
    if (i >= E_EDGES) return;
    int d = dst[i];
    int pos = offs[d] + atomicAdd(&cnt[d], 1);
    esrc[pos] = src[i];
}

// ---------- h = x @ W, fp32 register-blocked ----------
// Block: 256 thr, 64-row tile, full 128 cols. Thread: 4 rows x 8 cols.
// K staged in chunks of 16: xT[16][64] (transposed) + wS[16][128] in LDS.
__global__ __launch_bounds__(256) void gemm_f32_kernel(const float* __restrict__ x,
                                                       const float* __restrict__ W,
                                                       float* __restrict__ h, int M) {
    __shared__ float xT[16][64];
    __shared__ float wS[16][128];
    int t = threadIdx.x;
    int row0 = blockIdx.x * 64;
    int c0 = (t & 15) * 8;
    int r0 = (t >> 4) * 4;
    int xr = t >> 2;        // 0..63 (staging row)
    int xk = (t & 3) * 4;   // staging k offset
    int wr = t >> 4;        // 0..15 (staging W row within chunk)
    int wc = (t & 15) * 8;

    float acc[4][8];
#pragma unroll
    for (int i = 0; i < 4; i++)
#pragma unroll
        for (int j = 0; j < 8; j++) acc[i][j] = 0.f;

    for (int kc = 0; kc < 8; ++kc) {
        float4 xa = make_float4(0.f, 0.f, 0.f, 0.f);
        int grow = row0 + xr;
        if (grow < M) xa = *(const float4*)(x + grow * 128 + kc * 16 + xk);
        xT[xk + 0][xr] = xa.x; xT[xk + 1][xr] = xa.y;
        xT[xk + 2][xr] = xa.z; xT[xk + 3][xr] = xa.w;
        float4 wa = *(const float4*)(W + (kc * 16 + wr) * 128 + wc);
        float4 wb = *(const float4*)(W + (kc * 16 + wr) * 128 + wc + 4);
        *(float4*)&wS[wr][wc] = wa;
        *(float4*)&wS[wr][wc + 4] = wb;
        __syncthreads();
#pragma unroll
        for (int k = 0; k < 16; ++k) {
            float4 a = *(const float4*)&xT[k][r0];
            float4 b0 = *(const float4*)&wS[k][c0];
            float4 b1 = *(const float4*)&wS[k][c0 + 4];
            float av[4] = {a.x, a.y, a.z, a.w};
            float bv[8] = {b0.x, b0.y, b0.z, b0.w, b1.x, b1.y, b1.z, b1.w};
#pragma unroll
            for (int i = 0; i < 4; i++)
#pragma unroll
                for (int j = 0; j < 8; j++) acc[i][j] = fmaf(av[i], bv[j], acc[i][j]);
        }
        __syncthreads();
    }

#pragma unroll
    for (int i = 0; i < 4; i++) {
        int row = row0 + r0 + i;
        if (row < M) {
            *(float4*)(h + row * 128 + c0)     = make_float4(acc[i][0], acc[i][1], acc[i][2], acc[i][3]);
            *(float4*)(h + row * 128 + c0 + 4) = make_float4(acc[i][4], acc[i][5], acc[i][6], acc[i][7]);
        }
    }
}

// ---------- el/er scores ----------
__global__ __launch_bounds__(256) void scores_kernel(const float* __restrict__ h,
                                                     const float* __restrict__ params,
                                                     float* __restrict__ el,
                                                     float* __restrict__ er, int M) {
    int node = (blockIdx.x * 256 + threadIdx.x) >> 6;
    int lane = threadIdx.x & 63;
    if (node >= M) return;
    const float* al = params + 16384;
    const float* ar = params + 16512;
    const float* hr = h + node * 128;
    float h0 = hr[lane], h1 = hr[lane + 64];
    float pl0 = h0 * al[lane], pl1 = h1 * al[lane + 64];
    float pr0 = h0 * ar[lane], pr1 = h1 * ar[lane + 64];
#pragma unroll
    for (int off = 16; off >= 1; off >>= 1) {
        pl0 += __shfl_xor(pl0, off);
        pl1 += __shfl_xor(pl1, off);
        pr0 += __shfl_xor(pr0, off);
        pr1 += __shfl_xor(pr1, off);
    }
    if (lane == 0)  { el[node * 4 + 0] = pl0; el[node * 4 + 2] = pl1;
                      er[node * 4 + 0] = pr0; er[node * 4 + 2] = pr1; }
    if (lane == 32) { el[node * 4 + 1] = pl0; el[node * 4 + 3] = pl1;
                      er[node * 4 + 1] = pr0; er[node * 4 + 3] = pr1; }
}

__device__ __forceinline__ float leaky(float v) { return v > 0.f ? v : v * NEG_SLOPE; }

// ---------- fused: two-pass softmax aggregation + bias + LayerNorm + ELU ----------
// One 64-lane wave per dst node; lane owns channels (2*lane, 2*lane+1), head = lane>>4.
template <bool LAST>
__global__ __launch_bounds__(256) void agg_ln_kernel(const int* __restrict__ offs,
                                                     const int* __restrict__ esrc,
                                                     const float* __restrict__ el,
                                                     const float* __restrict__ er,
                                                     const float* __restrict__ h,
                                                     const float* __restrict__ params,
                                                     const unsigned int* __restrict__ flag,
                                                     float* __restrict__ x_next,
                                                     void* __restrict__ out) {
    int node = (blockIdx.x * 256 + threadIdx.x) >> 6;
    int lane = threadIdx.x & 63;
    if (node >= N_NODES) return;
    int hd = lane >> 4;
    int c0 = lane * 2;
    float er_d = er[node * 4 + hd];
    int e0 = offs[node], e1 = offs[node + 1];

    // pass 1: max (only el reads — broadcast within lane quads)
    float m = -INFINITY;
    {
        int e = e0;
        for (; e + 1 < e1; e += 2) {
            float va = leaky(el[esrc[e] * 4 + hd] + er_d);
            float vb = leaky(el[esrc[e + 1] * 4 + hd] + er_d);
            m = fmaxf(m, fmaxf(va, vb));
        }
        if (e < e1) m = fmaxf(m, leaky(el[esrc[e] * 4 + hd] + er_d));
    }

    // pass 2: independent iterations, 2-way unrolled for MLP
    float l = 0.f, a0 = 0.f, a1 = 0.f;
    {
        int e = e0;
        for (; e + 1 < e1; e += 2) {
            int s0 = esrc[e], s1 = esrc[e + 1];
            float va = leaky(el[s0 * 4 + hd] + er_d);
            float vb = leaky(el[s1 * 4 + hd] + er_d);
            float2 h0 = *(const float2*)(h + s0 * 128 + c0);
            float2 h1 = *(const float2*)(h + s1 * 128 + c0);
            float ea = __expf(va - m), eb = __expf(vb - m);
            l += ea + eb;
            a0 = fmaf(ea, h0.x, fmaf(eb, h1.x, a0));
            a1 = fmaf(ea, h0.y, fmaf(eb, h1.y, a1));
        }
        if (e < e1) {
            int s0 = esrc[e];
            float va = leaky(el[s0 * 4 + hd] + er_d);
            float2 h0 = *(const float2*)(h + s0 * 128 + c0);
            float ea = __expf(va - m);
            l += ea;
            a0 = fmaf(ea, h0.x, a0);
            a1 = fmaf(ea, h0.y, a1);
        }
    }

    float inv = 1.f / fmaxf(l, 1e-9f);
    const float* b  = params + 16640;
    const float* g  = params + 16768;
    const float* be = params + 16896;
    float v0 = fmaf(a0, inv, b[c0]);
    float v1 = fmaf(a1, inv, b[c0 + 1]);

    float s = v0 + v1;
#pragma unroll
    for (int off = 32; off >= 1; off >>= 1) s += __shfl_xor(s, off);
    float mu = s * (1.f / 128.f);
    float q0 = v0 - mu, q1 = v1 - mu;
    float vs = q0 * q0 + q1 * q1;
#pragma unroll
    for (int off = 32; off >= 1; off >>= 1) vs += __shfl_xor(vs, off);
    float rstd = rsqrtf(vs * (1.f / 128.f) + LN_EPS);
    float y0 = q0 * rstd * g[c0] + be[c0];
    float y1 = q1 * rstd * g[c0 + 1] + be[c0 + 1];
    y0 = y0 > 0.f ? y0 : expm1f(y0);
    y1 = y1 > 0.f ? y1 : expm1f(y1);

    if (LAST) {
        if (*flag) {  // bf16 output — channels (2*lane, 2*lane+1), correct in this mapping
            __hip_bfloat16 o0 = __float2bfloat16(y0);
            __hip_bfloat16 o1 = __float2bfloat16(y1);
            unsigned int packed = (unsigned int)(*(unsigned short*)&o0)
                                | ((unsigned int)(*(unsigned short*)&o1) << 16);
            ((unsigned int*)out)[node * 64 + lane] = packed;
        } else {      // fp32 output
            ((float2*)out)[node * 64 + lane] = make_float2(y0, y1);
        }
    } else {
        ((float2*)x_next)[node * 64 + lane] = make_float2(y0, y1);
    }
}

extern "C" void kernel_launch(void* const* d_in, const int* in_sizes, int n_in,
                              void* d_out, int out_size, void* d_ws, size_t ws_size,
                              hipStream_t stream) {
    const void* features = d_in[0];
    const int* src = (const int*)d_in[1];
    const int* dst = (const int*)d_in[2];

    char* w = (char*)d_ws;
    float* xbuf = (float*)w;                                // 25.6 MB (x / x_next)
    float* hbuf = (float*)(w + 25600000);                   // 25.6 MB (h)
    float* el = (float*)(w + 51200000);                     // 800 KB
    float* er = el + N_NODES * HEADS;                       // 800 KB
    float* params0 = er + N_NODES * HEADS;                  // 68 KB
    float* params1 = params0 + PARAM_FLOATS;                // 68 KB
    int* offs = (int*)(params1 + PARAM_FLOATS);             // 50001
    int* deg  = offs + N_NODES + 1;                         // 50000
    int* esrc = deg + N_NODES;                              // 800000
    unsigned int* flag = (unsigned int*)(esrc + E_EDGES);

    detect_kernel<<<1, 256, 0, stream>>>((const unsigned int*)d_in[3], flag);
    cvt_feat_kernel<<<(N_NODES * HID + 255) / 256, 256, 0, stream>>>(features, flag, xbuf,
                                                                     N_NODES * HID);
    cvt_params_kernel<<<(PARAM_FLOATS + 255) / 256, 256, 0, stream>>>(
        d_in[3], d_in[4], d_in[5], d_in[6], d_in[7], d_in[8], flag, params0);
    cvt_params_kernel<<<(PARAM_FLOATS + 255) / 256, 256, 0, stream>>>(
        d_in[9], d_in[10], d_in[11], d_in[12], d_in[13], d_in[14], flag, params1);

    hipMemsetAsync(deg, 0, N_NODES * sizeof(int), stream);
    hist_kernel<<<(E_EDGES + 255) / 256, 256, 0, stream>>>(dst, deg);
    scan_kernel<<<1, 1024, 0, stream>>>(deg, offs);
    hipMemsetAsync(deg, 0, N_NODES * sizeof(int), stream);
    scatter_kernel<<<(E_EDGES + 255) / 256, 256, 0, stream>>>(src, dst, offs, deg, esrc);

    for (int l = 0; l < 2; ++l) {
        float* params = (l == 0) ? params0 : params1;
        gemm_f32_kernel<<<(N_NODES + 63) / 64, 256, 0, stream>>>(xbuf, params, hbuf, N_NODES);
        scores_kernel<<<(N_NODES * 64 + 255) / 256, 256, 0, stream>>>(hbuf, params, el, er,
                                                                      N_NODES);
        if (l == 0) {
            agg_ln_kernel<false><<<(N_NODES * 64 + 255) / 256, 256, 0, stream>>>(
                offs, esrc, el, er, hbuf, params, flag, xbuf, nullptr);
        } else {
            agg_ln_kernel<true><<<(N_NODES * 64 + 255) / 256, 256, 0, stream>>>(
                offs, esrc, el, er, hbuf, params, flag, nullptr, d_out);
        }
    }
}